// Round 7
// baseline (312.237 us; speedup 1.0000x reference)
//
#include <hip/hip_runtime.h>
#include <hip/hip_cooperative_groups.h>

namespace cg = cooperative_groups;

// MGN_NET: 3x NNConv(mean) + ReLU, then pairwise-L1 CBT [35x35]. All fp32.
// ONE cooperative dispatch (6 phases, grid.sync between) + 6-kernel fallback.
// ws layout (floats): agg1@0[8960], agg2@8960[8960], agg3@17920[2240],
//   cnt@20160[35] (zero span 20195), lin2T@20224[65536], x2m@85760[8960],
//   x3@94720[2240]

#define NN 35
#define NE 1190
#define TE 10   // edges per edge-group; 1190 = 119*10
#define NG 119
#define NU2 476  // msg2 units: 119 eg x 4 og
#define NU3 511  // msg3: 476 msg units + 35 x2m-writer units
#define NB 256
#define NT 512
#define GSZ (NB * NT)

#define OFF_AGG1 0
#define OFF_AGG2 8960
#define OFF_AGG3 17920
#define OFF_CNT  20160
#define ZERO_N   20195
#define OFF_L2T  20224
#define OFF_X2M  85760
#define OFF_X3   94720

__global__ __launch_bounds__(NT, 2) void mega_k(
    const float* __restrict__ x, const float* __restrict__ ea,
    const int* __restrict__ ei,
    const float* __restrict__ w1, const float* __restrict__ b1w,
    const float* __restrict__ lin1, const float* __restrict__ b1,
    const float* __restrict__ w2, const float* __restrict__ b2w,
    const float* __restrict__ lin2, const float* __restrict__ b2,
    const float* __restrict__ w3, const float* __restrict__ b3w,
    const float* __restrict__ lin3, const float* __restrict__ b3,
    float* __restrict__ ws, float* __restrict__ out) {
    cg::grid_group grid = cg::this_grid();
    __shared__ float x1r[TE][256];
    __shared__ float xs[TE][256];
    __shared__ float eas[TE][6];
    __shared__ int srcs[TE], dsts[TE];
    __shared__ float part[7][TE][64];

    float* agg1  = ws + OFF_AGG1;
    float* agg2  = ws + OFF_AGG2;
    float* agg3  = ws + OFF_AGG3;
    float* cnt   = ws + OFF_CNT;
    float* lin2T = ws + OFF_L2T;
    float* x2m   = ws + OFF_X2M;
    float* x3v   = ws + OFF_X3;

    const int tid = threadIdx.x;
    const int bid = blockIdx.x;
    const int gtid = bid * NT + tid;
    const int ol = tid & 63;
    const int ic = tid >> 6;  // 0..7

    // ---- phase 0: zero accumulators + transpose lin2 (coalesced reads) ----
    for (int idx = gtid; idx < ZERO_N; idx += GSZ) ws[idx] = 0.f;
    for (int idx = gtid; idx < 65536; idx += GSZ) {
        int o = idx >> 8, i = idx & 255;
        lin2T[i * 256 + o] = lin2[idx];
    }
    grid.sync();

    // ---- phase 1: msg1 scatter (c_in=1) ----
    for (int idx = gtid; idx < NE * 256; idx += GSZ) {
        int e = idx >> 8, o = idx & 255;
        int src = ei[e], dst = ei[NE + e];
        const float* eap = ea + e * 6;
        const float* w = w1 + o * 6;
        float d = b1w[o];
#pragma unroll
        for (int v = 0; v < 6; v++) d = fmaf(eap[v], w[v], d);
        atomicAdd(agg1 + dst * 256 + o, x[src] * fmaxf(d, 0.f));
        if (o == 0) atomicAdd(cnt + dst, 1.f);
    }
    grid.sync();

    // ---- phase 2: msg2 (+x1 recompute), units {eg,og} ----
    for (int u = bid; u < NU2; u += NB) {
        __syncthreads();  // protect srcs/dsts/part from previous unit readers
        int eg = u >> 2, og = u & 3;
        int e0 = eg * TE;
        if (tid < TE) { srcs[tid] = ei[e0 + tid]; dsts[tid] = ei[NE + e0 + tid]; }
        if (tid >= 64 && tid < 64 + TE * 6) {
            int t = tid - 64;
            eas[t / 6][t % 6] = ea[e0 * 6 + t];
        }
        __syncthreads();
        for (int idx = tid; idx < TE * 256; idx += NT) {
            int te = idx >> 8, i = idx & 255;
            int s = srcs[te];
            float c = fmaxf(cnt[s], 1.f);
            float v = agg1[s * 256 + i] / c + x[s] * lin1[i] + b1[i];
            xs[te][i] = fmaxf(v, 0.f);
        }
        __syncthreads();
        int o = og * 64 + ol;
        float eareg[TE][6];
#pragma unroll
        for (int te = 0; te < TE; te++)
#pragma unroll
            for (int v = 0; v < 6; v++) eareg[te][v] = eas[te][v];
        float acc[TE] = {};
        for (int ii = 0; ii < 32; ii++) {
            int i = ic * 32 + ii;
            const float* w = w2 + (size_t)(i * 256 + o) * 6;
            float2 wa = *(const float2*)w;
            float2 wb = *(const float2*)(w + 2);
            float2 wc = *(const float2*)(w + 4);
            float b = b2w[i * 256 + o];
#pragma unroll
            for (int te = 0; te < TE; te += 2) {
                float dx = b, dy = b;
                dx = fmaf(eareg[te][0], wa.x, dx); dy = fmaf(eareg[te + 1][0], wa.x, dy);
                dx = fmaf(eareg[te][1], wa.y, dx); dy = fmaf(eareg[te + 1][1], wa.y, dy);
                dx = fmaf(eareg[te][2], wb.x, dx); dy = fmaf(eareg[te + 1][2], wb.x, dy);
                dx = fmaf(eareg[te][3], wb.y, dx); dy = fmaf(eareg[te + 1][3], wb.y, dy);
                dx = fmaf(eareg[te][4], wc.x, dx); dy = fmaf(eareg[te + 1][4], wc.x, dy);
                dx = fmaf(eareg[te][5], wc.y, dx); dy = fmaf(eareg[te + 1][5], wc.y, dy);
                dx = fmaxf(dx, 0.f);               dy = fmaxf(dy, 0.f);
                acc[te] = fmaf(xs[te][i], dx, acc[te]);
                acc[te + 1] = fmaf(xs[te + 1][i], dy, acc[te + 1]);
            }
        }
        if (ic > 0) {
#pragma unroll
            for (int te = 0; te < TE; te++) part[ic - 1][te][ol] = acc[te];
        }
        __syncthreads();
        if (ic == 0) {
#pragma unroll
            for (int te = 0; te < TE; te++) {
                float s = acc[te];
#pragma unroll
                for (int p = 0; p < 7; p++) s += part[p][te][ol];
                atomicAdd(agg2 + dsts[te] * 256 + o, s);
            }
        }
    }
    grid.sync();

    // ---- phase 3: msg3 (+x2 slice via lin2T) + 35 x2m writer units ----
    for (int u = bid; u < NU3; u += NB) {
        __syncthreads();
        if (u >= NU2) {
            // x2m writer for node n
            int n = u - NU2;
            float c = fmaxf(cnt[n], 1.f);
            if (tid < 256) {
                float v = agg1[n * 256 + tid] / c + x[n] * lin1[tid] + b1[tid];
                x1r[0][tid] = fmaxf(v, 0.f);
            }
            __syncthreads();
            int o = tid & 255, icw = tid >> 8;
            float s = 0.f;
            for (int ii = 0; ii < 128; ii++) {
                int i = icw * 128 + ii;
                s = fmaf(lin2T[i * 256 + o], x1r[0][i], s);
            }
            float* p2 = &part[0][0][0];
            if (icw == 1) p2[o] = s;
            __syncthreads();
            if (icw == 0) {
                float v = agg2[n * 256 + o] / c + s + p2[o] + b2[o];
                x2m[n * 256 + o] = fmaxf(v, 0.f);
            }
            continue;
        }
        int eg = u >> 2, ig = u & 3;
        int e0 = eg * TE;
        if (tid < TE) { srcs[tid] = ei[e0 + tid]; dsts[tid] = ei[NE + e0 + tid]; }
        if (tid >= 64 && tid < 64 + TE * 6) {
            int t = tid - 64;
            eas[t / 6][t % 6] = ea[e0 * 6 + t];
        }
        __syncthreads();
        for (int idx = tid; idx < TE * 256; idx += NT) {
            int te = idx >> 8, i = idx & 255;
            int s = srcs[te];
            float c = fmaxf(cnt[s], 1.f);
            float v = agg1[s * 256 + i] / c + x[s] * lin1[i] + b1[i];
            x1r[te][i] = fmaxf(v, 0.f);
        }
        __syncthreads();
        int o2 = ig * 64 + ol;
        {   // x2 slice: xs[te][ol] = relu(agg2/c + lin2T-col dot + b2)
            float acc2[TE] = {};
            for (int ii = 0; ii < 32; ii++) {
                int i = ic * 32 + ii;
                float w = lin2T[i * 256 + o2];
#pragma unroll
                for (int te = 0; te < TE; te++)
                    acc2[te] = fmaf(w, x1r[te][i], acc2[te]);
            }
            if (ic > 0) {
#pragma unroll
                for (int te = 0; te < TE; te++) part[ic - 1][te][ol] = acc2[te];
            }
            __syncthreads();
            if (ic == 0) {
#pragma unroll
                for (int te = 0; te < TE; te++) {
                    float ssum = acc2[te];
#pragma unroll
                    for (int p = 0; p < 7; p++) ssum += part[p][te][ol];
                    int s = srcs[te];
                    float c = fmaxf(cnt[s], 1.f);
                    float v = agg2[s * 256 + o2] / c + ssum + b2[o2];
                    xs[te][ol] = fmaxf(v, 0.f);
                }
            }
            __syncthreads();
        }
        float eareg[TE][6];
#pragma unroll
        for (int te = 0; te < TE; te++)
#pragma unroll
            for (int v = 0; v < 6; v++) eareg[te][v] = eas[te][v];
        float acc[TE] = {};
        for (int jj = 0; jj < 8; jj++) {
            int ii = ic * 8 + jj;
            int i = ig * 64 + ii;
            const float* w = w3 + (size_t)(i * 64 + ol) * 6;
            float2 wa = *(const float2*)w;
            float2 wb = *(const float2*)(w + 2);
            float2 wc = *(const float2*)(w + 4);
            float b = b3w[i * 64 + ol];
#pragma unroll
            for (int te = 0; te < TE; te += 2) {
                float dx = b, dy = b;
                dx = fmaf(eareg[te][0], wa.x, dx); dy = fmaf(eareg[te + 1][0], wa.x, dy);
                dx = fmaf(eareg[te][1], wa.y, dx); dy = fmaf(eareg[te + 1][1], wa.y, dy);
                dx = fmaf(eareg[te][2], wb.x, dx); dy = fmaf(eareg[te + 1][2], wb.x, dy);
                dx = fmaf(eareg[te][3], wb.y, dx); dy = fmaf(eareg[te + 1][3], wb.y, dy);
                dx = fmaf(eareg[te][4], wc.x, dx); dy = fmaf(eareg[te + 1][4], wc.x, dy);
                dx = fmaf(eareg[te][5], wc.y, dx); dy = fmaf(eareg[te + 1][5], wc.y, dy);
                dx = fmaxf(dx, 0.f);               dy = fmaxf(dy, 0.f);
                acc[te] = fmaf(xs[te][ii], dx, acc[te]);
                acc[te + 1] = fmaf(xs[te + 1][ii], dy, acc[te + 1]);
            }
        }
        if (ic > 0) {
#pragma unroll
            for (int te = 0; te < TE; te++) part[ic - 1][te][ol] = acc[te];
        }
        __syncthreads();
        if (ic == 0) {
#pragma unroll
            for (int te = 0; te < TE; te++) {
                float s = acc[te];
#pragma unroll
                for (int p = 0; p < 7; p++) s += part[p][te][ol];
                atomicAdd(agg3 + dsts[te] * 64 + ol, s);
            }
        }
    }
    grid.sync();

    // ---- phase 4: x3 (blocks 0..34) ----
    if (bid < NN) {
        int n = bid;
        if (tid < 256) x1r[0][tid] = x2m[n * 256 + tid];
        __syncthreads();
        const float4* w = (const float4*)(lin3 + (size_t)ol * 256 + ic * 32);
        float s = 0.f;
#pragma unroll
        for (int k = 0; k < 8; k++) {
            float4 wv = w[k];
            int i = ic * 32 + k * 4;
            s = fmaf(wv.x, x1r[0][i], s);
            s = fmaf(wv.y, x1r[0][i + 1], s);
            s = fmaf(wv.z, x1r[0][i + 2], s);
            s = fmaf(wv.w, x1r[0][i + 3], s);
        }
        if (ic > 0) part[ic - 1][0][ol] = s;
        __syncthreads();
        if (ic == 0) {
            float tot = s;
#pragma unroll
            for (int p = 0; p < 7; p++) tot += part[p][0][ol];
            float c = fmaxf(cnt[n], 1.f);
            x3v[n * 64 + ol] = fmaxf(agg3[n * 64 + ol] / c + tot + b3[ol], 0.f);
        }
    }
    grid.sync();

    // ---- phase 5: cbt ----
    for (int p = gtid; p < NN * NN; p += GSZ) {
        int i = p / NN, j = p % NN;
        const float* a = x3v + i * 64;
        const float* bb = x3v + j * 64;
        float s = 0.f;
#pragma unroll
        for (int f = 0; f < 64; f++) s += fabsf(a[f] - bb[f]);
        out[p] = s;
    }
}

// ------------------- fallback pipeline (round-6, proven) -------------------
__global__ __launch_bounds__(256) void prep_k(float* __restrict__ ws,
                                              const float* __restrict__ lin2) {
    int b = blockIdx.x, t = threadIdx.x;
    if (b < 80) {
        int idx = b * 256 + t;
        if (idx < ZERO_N) ws[idx] = 0.f;
    } else {
        int i = b - 80;
        ws[OFF_L2T + i * 256 + t] = lin2[t * 256 + i];
    }
}

__global__ __launch_bounds__(512) void msg1_k(
    const float* __restrict__ x, const float* __restrict__ ea,
    const int* __restrict__ ei, const float* __restrict__ w1,
    const float* __restrict__ b1w, float* __restrict__ agg1,
    float* __restrict__ cnt) {
    int tid = threadIdx.x;
    int e = blockIdx.x * 2 + (tid >> 8);
    int o = tid & 255;
    int src = ei[e];
    int dst = ei[NE + e];
    float xs = x[src];
    const float* eap = ea + e * 6;
    const float* w = w1 + o * 6;
    float d = b1w[o];
#pragma unroll
    for (int v = 0; v < 6; v++) d = fmaf(eap[v], w[v], d);
    atomicAdd(agg1 + dst * 256 + o, xs * fmaxf(d, 0.f));
    if (o == 0) atomicAdd(cnt + dst, 1.0f);
}

__global__ __launch_bounds__(512, 4) void msg2x1_k(
    const float* __restrict__ x, const float* __restrict__ ea,
    const int* __restrict__ ei, const float* __restrict__ lin1,
    const float* __restrict__ b1, const float* __restrict__ agg1,
    const float* __restrict__ cnt, const float* __restrict__ w2,
    const float* __restrict__ b2w, float* __restrict__ agg2) {
    __shared__ float xs[TE][256];
    __shared__ float eas[TE][6];
    __shared__ int srcs[TE], dsts[TE];
    __shared__ float part[7][TE][64];
    int tid = threadIdx.x;
    int eg = blockIdx.x >> 2, og = blockIdx.x & 3;
    int e0 = eg * TE;
    if (tid < TE) { srcs[tid] = ei[e0 + tid]; dsts[tid] = ei[NE + e0 + tid]; }
    if (tid >= 64 && tid < 64 + TE * 6) {
        int t = tid - 64;
        eas[t / 6][t % 6] = ea[e0 * 6 + t];
    }
    __syncthreads();
    for (int idx = tid; idx < TE * 256; idx += 512) {
        int te = idx >> 8, i = idx & 255;
        int s = srcs[te];
        float c = fmaxf(cnt[s], 1.f);
        float v = agg1[s * 256 + i] / c + x[s] * lin1[i] + b1[i];
        xs[te][i] = fmaxf(v, 0.f);
    }
    __syncthreads();
    int ol = tid & 63;
    int o = og * 64 + ol;
    int ic = tid >> 6;
    float eareg[TE][6];
#pragma unroll
    for (int te = 0; te < TE; te++)
#pragma unroll
        for (int v = 0; v < 6; v++) eareg[te][v] = eas[te][v];
    float acc[TE] = {};
    for (int ii = 0; ii < 32; ii++) {
        int i = ic * 32 + ii;
        const float* w = w2 + (size_t)(i * 256 + o) * 6;
        float2 wa = *(const float2*)w;
        float2 wb = *(const float2*)(w + 2);
        float2 wc = *(const float2*)(w + 4);
        float b = b2w[i * 256 + o];
#pragma unroll
        for (int te = 0; te < TE; te += 2) {
            float dx = b, dy = b;
            dx = fmaf(eareg[te][0], wa.x, dx); dy = fmaf(eareg[te + 1][0], wa.x, dy);
            dx = fmaf(eareg[te][1], wa.y, dx); dy = fmaf(eareg[te + 1][1], wa.y, dy);
            dx = fmaf(eareg[te][2], wb.x, dx); dy = fmaf(eareg[te + 1][2], wb.x, dy);
            dx = fmaf(eareg[te][3], wb.y, dx); dy = fmaf(eareg[te + 1][3], wb.y, dy);
            dx = fmaf(eareg[te][4], wc.x, dx); dy = fmaf(eareg[te + 1][4], wc.x, dy);
            dx = fmaf(eareg[te][5], wc.y, dx); dy = fmaf(eareg[te + 1][5], wc.y, dy);
            dx = fmaxf(dx, 0.f);               dy = fmaxf(dy, 0.f);
            acc[te] = fmaf(xs[te][i], dx, acc[te]);
            acc[te + 1] = fmaf(xs[te + 1][i], dy, acc[te + 1]);
        }
    }
    if (ic > 0) {
#pragma unroll
        for (int te = 0; te < TE; te++) part[ic - 1][te][ol] = acc[te];
    }
    __syncthreads();
    if (ic == 0) {
#pragma unroll
        for (int te = 0; te < TE; te++) {
            float s = acc[te];
#pragma unroll
            for (int p = 0; p < 7; p++) s += part[p][te][ol];
            atomicAdd(agg2 + dsts[te] * 256 + o, s);
        }
    }
}

__global__ __launch_bounds__(512, 4) void msg3x2_k(
    const float* __restrict__ x, const float* __restrict__ ea,
    const int* __restrict__ ei, const float* __restrict__ lin1,
    const float* __restrict__ b1, const float* __restrict__ agg1,
    const float* __restrict__ cnt, const float* __restrict__ lin2T,
    const float* __restrict__ b2, const float* __restrict__ agg2,
    const float* __restrict__ w3, const float* __restrict__ b3w,
    float* __restrict__ agg3, float* __restrict__ x2m) {
    __shared__ float x1r[TE][256];
    __shared__ float xs[TE][64];
    __shared__ float eas[TE][6];
    __shared__ int srcs[TE], dsts[TE];
    __shared__ float part[7][TE][64];
    int tid = threadIdx.x;

    if (blockIdx.x >= NU2) {
        int n = blockIdx.x - NU2;
        float c = fmaxf(cnt[n], 1.f);
        if (tid < 256) {
            float v = agg1[n * 256 + tid] / c + x[n] * lin1[tid] + b1[tid];
            x1r[0][tid] = fmaxf(v, 0.f);
        }
        __syncthreads();
        int o = tid & 255, ic = tid >> 8;
        float s = 0.f;
        for (int ii = 0; ii < 128; ii++) {
            int i = ic * 128 + ii;
            s = fmaf(lin2T[i * 256 + o], x1r[0][i], s);
        }
        float* p2 = &part[0][0][0];
        if (ic == 1) p2[o] = s;
        __syncthreads();
        if (ic == 0) {
            float v = agg2[n * 256 + o] / c + s + p2[o] + b2[o];
            x2m[n * 256 + o] = fmaxf(v, 0.f);
        }
        return;
    }

    int eg = blockIdx.x >> 2, ig = blockIdx.x & 3;
    int e0 = eg * TE;
    if (tid < TE) { srcs[tid] = ei[e0 + tid]; dsts[tid] = ei[NE + e0 + tid]; }
    if (tid >= 64 && tid < 64 + TE * 6) {
        int t = tid - 64;
        eas[t / 6][t % 6] = ea[e0 * 6 + t];
    }
    __syncthreads();
    for (int idx = tid; idx < TE * 256; idx += 512) {
        int te = idx >> 8, i = idx & 255;
        int s = srcs[te];
        float c = fmaxf(cnt[s], 1.f);
        float v = agg1[s * 256 + i] / c + x[s] * lin1[i] + b1[i];
        x1r[te][i] = fmaxf(v, 0.f);
    }
    __syncthreads();
    int ol = tid & 63;
    int ic = tid >> 6;
    int o2 = ig * 64 + ol;
    {
        float acc2[TE] = {};
        for (int ii = 0; ii < 32; ii++) {
            int i = ic * 32 + ii;
            float w = lin2T[i * 256 + o2];
#pragma unroll
            for (int te = 0; te < TE; te++)
                acc2[te] = fmaf(w, x1r[te][i], acc2[te]);
        }
        if (ic > 0) {
#pragma unroll
            for (int te = 0; te < TE; te++) part[ic - 1][te][ol] = acc2[te];
        }
        __syncthreads();
        if (ic == 0) {
#pragma unroll
            for (int te = 0; te < TE; te++) {
                float ssum = acc2[te];
#pragma unroll
                for (int p = 0; p < 7; p++) ssum += part[p][te][ol];
                int s = srcs[te];
                float c = fmaxf(cnt[s], 1.f);
                float v = agg2[s * 256 + o2] / c + ssum + b2[o2];
                xs[te][ol] = fmaxf(v, 0.f);
            }
        }
        __syncthreads();
    }
    float eareg[TE][6];
#pragma unroll
    for (int te = 0; te < TE; te++)
#pragma unroll
        for (int v = 0; v < 6; v++) eareg[te][v] = eas[te][v];
    float acc[TE] = {};
    for (int jj = 0; jj < 8; jj++) {
        int ii = ic * 8 + jj;
        int i = ig * 64 + ii;
        const float* w = w3 + (size_t)(i * 64 + ol) * 6;
        float2 wa = *(const float2*)w;
        float2 wb = *(const float2*)(w + 2);
        float2 wc = *(const float2*)(w + 4);
        float b = b3w[i * 64 + ol];
#pragma unroll
        for (int te = 0; te < TE; te += 2) {
            float dx = b, dy = b;
            dx = fmaf(eareg[te][0], wa.x, dx); dy = fmaf(eareg[te + 1][0], wa.x, dy);
            dx = fmaf(eareg[te][1], wa.y, dx); dy = fmaf(eareg[te + 1][1], wa.y, dy);
            dx = fmaf(eareg[te][2], wb.x, dx); dy = fmaf(eareg[te + 1][2], wb.x, dy);
            dx = fmaf(eareg[te][3], wb.y, dx); dy = fmaf(eareg[te + 1][3], wb.y, dy);
            dx = fmaf(eareg[te][4], wc.x, dx); dy = fmaf(eareg[te + 1][4], wc.x, dy);
            dx = fmaf(eareg[te][5], wc.y, dx); dy = fmaf(eareg[te + 1][5], wc.y, dy);
            dx = fmaxf(dx, 0.f);               dy = fmaxf(dy, 0.f);
            acc[te] = fmaf(xs[te][ii], dx, acc[te]);
            acc[te + 1] = fmaf(xs[te + 1][ii], dy, acc[te + 1]);
        }
    }
    if (ic > 0) {
#pragma unroll
        for (int te = 0; te < TE; te++) part[ic - 1][te][ol] = acc[te];
    }
    __syncthreads();
    if (ic == 0) {
#pragma unroll
        for (int te = 0; te < TE; te++) {
            float s = acc[te];
#pragma unroll
            for (int p = 0; p < 7; p++) s += part[p][te][ol];
            atomicAdd(agg3 + dsts[te] * 64 + ol, s);
        }
    }
}

__global__ __launch_bounds__(256) void x3_k(
    const float* __restrict__ x2m, const float* __restrict__ lin3,
    const float* __restrict__ b3, const float* __restrict__ agg3,
    const float* __restrict__ cnt, float* __restrict__ x3) {
    __shared__ float xr[256];
    __shared__ float part[3][64];
    int n = blockIdx.x, tid = threadIdx.x;
    int o = tid & 63, ic = tid >> 6;
    xr[tid] = x2m[n * 256 + tid];
    __syncthreads();
    const float4* w = (const float4*)(lin3 + (size_t)o * 256 + ic * 64);
    float s = 0.f;
#pragma unroll
    for (int k = 0; k < 16; k++) {
        float4 wv = w[k];
        int i = ic * 64 + k * 4;
        s = fmaf(wv.x, xr[i], s);
        s = fmaf(wv.y, xr[i + 1], s);
        s = fmaf(wv.z, xr[i + 2], s);
        s = fmaf(wv.w, xr[i + 3], s);
    }
    if (ic > 0) part[ic - 1][o] = s;
    __syncthreads();
    if (ic == 0) {
        float tot = s + part[0][o] + part[1][o] + part[2][o];
        float c = fmaxf(cnt[n], 1.f);
        x3[n * 64 + o] = fmaxf(agg3[n * 64 + o] / c + tot + b3[o], 0.f);
    }
}

__global__ __launch_bounds__(256) void cbt_k(const float* __restrict__ x3,
                                             float* __restrict__ out) {
    int t = blockIdx.x * 256 + threadIdx.x;
    if (t >= NN * NN) return;
    int i = t / NN, j = t % NN;
    const float* a = x3 + i * 64;
    const float* b = x3 + j * 64;
    float s = 0.f;
#pragma unroll
    for (int f = 0; f < 64; f++) s += fabsf(a[f] - b[f]);
    out[t] = s;
}

extern "C" void kernel_launch(void* const* d_in, const int* in_sizes, int n_in,
                              void* d_out, int out_size, void* d_ws, size_t ws_size,
                              hipStream_t stream) {
    const float* x    = (const float*)d_in[0];
    const float* ea   = (const float*)d_in[1];
    const int*   ei   = (const int*)d_in[2];
    const float* nn1w = (const float*)d_in[3];
    const float* nn1b = (const float*)d_in[4];
    const float* lin1 = (const float*)d_in[5];
    const float* b1   = (const float*)d_in[6];
    const float* nn2w = (const float*)d_in[7];
    const float* nn2b = (const float*)d_in[8];
    const float* lin2 = (const float*)d_in[9];
    const float* b2   = (const float*)d_in[10];
    const float* nn3w = (const float*)d_in[11];
    const float* nn3b = (const float*)d_in[12];
    const float* lin3 = (const float*)d_in[13];
    const float* b3   = (const float*)d_in[14];

    float* ws  = (float*)d_ws;
    float* out = (float*)d_out;

    void* args[] = {
        (void*)&x, (void*)&ea, (void*)&ei,
        (void*)&nn1w, (void*)&nn1b, (void*)&lin1, (void*)&b1,
        (void*)&nn2w, (void*)&nn2b, (void*)&lin2, (void*)&b2,
        (void*)&nn3w, (void*)&nn3b, (void*)&lin3, (void*)&b3,
        (void*)&ws, (void*)&out};
    hipError_t err = hipLaunchCooperativeKernel(
        (void*)mega_k, dim3(NB), dim3(NT), args, 0, stream);
    if (err != hipSuccess) {
        // fallback: proven 6-dispatch pipeline (same work)
        float* agg1  = ws + OFF_AGG1;
        float* agg2  = ws + OFF_AGG2;
        float* agg3  = ws + OFF_AGG3;
        float* cnt   = ws + OFF_CNT;
        float* lin2T = ws + OFF_L2T;
        float* x2m   = ws + OFF_X2M;
        float* x3v   = ws + OFF_X3;
        prep_k<<<336, 256, 0, stream>>>(ws, lin2);
        msg1_k<<<NE / 2, 512, 0, stream>>>(x, ea, ei, nn1w, nn1b, agg1, cnt);
        msg2x1_k<<<NG * 4, 512, 0, stream>>>(x, ea, ei, lin1, b1, agg1, cnt,
                                             nn2w, nn2b, agg2);
        msg3x2_k<<<NG * 4 + NN, 512, 0, stream>>>(x, ea, ei, lin1, b1, agg1,
                                                  cnt, lin2T, b2, agg2, nn3w,
                                                  nn3b, agg3, x2m);
        x3_k<<<NN, 256, 0, stream>>>(x2m, lin3, b3, agg3, cnt, x3v);
        cbt_k<<<(NN * NN + 255) / 256, 256, 0, stream>>>(x3v, out);
    }
}

// Round 8
// 156.414 us; speedup vs baseline: 1.9962x; 1.9962x over previous
//
#include <hip/hip_runtime.h>

// MGN_NET: 3x NNConv(mean) + ReLU, then pairwise-L1 CBT [35x35]. All fp32.
// 5 dispatches: prep(zero) -> msg1+transposes -> msg2(+x1) -> msg3(+x2) ->
//               x3cbt (35 blocks, each recomputes x3 via coalesced lin3T).
// NOTE: cooperative mega-kernel tried in R7: grid.sync ~35us each on gfx950
// (global atomic spin across 8 XCDs) -> 210us. Never again for ~30us of work.
// ws layout (floats): agg1@0[8960], agg2@8960[8960], agg3@17920[2240],
//   cnt@20160[35] (zero span 20195), lin2T@20224[65536], x2m@85760[8960],
//   lin3T@94720[16384]

#define NN 35
#define NE 1190
#define TE 10   // edges per edge-group; 1190 = 119*10
#define NG 119
#define NU2 476 // msg2 units: 119 eg x 4 og

#define OFF_AGG1 0
#define OFF_AGG2 8960
#define OFF_AGG3 17920
#define OFF_CNT  20160
#define ZERO_N   20195
#define OFF_L2T  20224
#define OFF_X2M  85760
#define OFF_L3T  94720

// prep: zero accumulators (80 blocks x 256)
__global__ __launch_bounds__(256) void prep_k(float* __restrict__ ws) {
    int idx = blockIdx.x * 256 + threadIdx.x;
    if (idx < ZERO_N) ws[idx] = 0.f;
}

// msg1 (blocks 0..594: 2 edges x 256 o) + weight transposes (blocks 595..754):
// lin2T[i][o]=lin2[o][i] (65536 elems), lin3T[i][o]=lin3[o][i] (16384 elems).
__global__ __launch_bounds__(512) void msg1t_k(
    const float* __restrict__ x, const float* __restrict__ ea,
    const int* __restrict__ ei, const float* __restrict__ w1,
    const float* __restrict__ b1w, const float* __restrict__ lin2,
    const float* __restrict__ lin3, float* __restrict__ ws) {
    int tid = threadIdx.x;
    if (blockIdx.x >= 595) {
        int idx = (blockIdx.x - 595) * 512 + tid;  // [0, 81920)
        if (idx < 65536) {
            int o = idx >> 8, i = idx & 255;
            ws[OFF_L2T + i * 256 + o] = lin2[idx];
        } else {
            int idx2 = idx - 65536;                // [0, 16384)
            int o = idx2 >> 8, i = idx2 & 255;     // lin3 is [64][256]
            ws[OFF_L3T + i * 64 + o] = lin3[idx2];
        }
        return;
    }
    float* agg1 = ws + OFF_AGG1;
    float* cnt  = ws + OFF_CNT;
    int e = blockIdx.x * 2 + (tid >> 8);
    int o = tid & 255;
    int src = ei[e];
    int dst = ei[NE + e];
    float xs = x[src];
    const float* eap = ea + e * 6;
    const float* w = w1 + o * 6;
    float d = b1w[o];
#pragma unroll
    for (int v = 0; v < 6; v++) d = fmaf(eap[v], w[v], d);
    atomicAdd(agg1 + dst * 256 + o, xs * fmaxf(d, 0.f));
    if (o == 0) atomicAdd(cnt + dst, 1.0f);
}

// Layer 2 (+x1 recompute): grid 119 eg x 4 og; block 512 = 64 ol x 8 ic.
__global__ __launch_bounds__(512, 4) void msg2x1_k(
    const float* __restrict__ x, const float* __restrict__ ea,
    const int* __restrict__ ei, const float* __restrict__ lin1,
    const float* __restrict__ b1, const float* __restrict__ agg1,
    const float* __restrict__ cnt, const float* __restrict__ w2,
    const float* __restrict__ b2w, float* __restrict__ agg2) {
    __shared__ float xs[TE][256];
    __shared__ float eas[TE][6];
    __shared__ int srcs[TE], dsts[TE];
    __shared__ float part[7][TE][64];
    int tid = threadIdx.x;
    int eg = blockIdx.x >> 2, og = blockIdx.x & 3;
    int e0 = eg * TE;
    if (tid < TE) { srcs[tid] = ei[e0 + tid]; dsts[tid] = ei[NE + e0 + tid]; }
    if (tid >= 64 && tid < 64 + TE * 6) {
        int t = tid - 64;
        eas[t / 6][t % 6] = ea[e0 * 6 + t];
    }
    __syncthreads();
    for (int idx = tid; idx < TE * 256; idx += 512) {
        int te = idx >> 8, i = idx & 255;
        int s = srcs[te];
        float c = fmaxf(cnt[s], 1.f);
        float v = agg1[s * 256 + i] / c + x[s] * lin1[i] + b1[i];
        xs[te][i] = fmaxf(v, 0.f);
    }
    __syncthreads();
    int ol = tid & 63;
    int o = og * 64 + ol;
    int ic = tid >> 6;
    float eareg[TE][6];
#pragma unroll
    for (int te = 0; te < TE; te++)
#pragma unroll
        for (int v = 0; v < 6; v++) eareg[te][v] = eas[te][v];
    float acc[TE] = {};
    for (int ii = 0; ii < 32; ii++) {
        int i = ic * 32 + ii;
        const float* w = w2 + (size_t)(i * 256 + o) * 6;
        float2 wa = *(const float2*)w;
        float2 wb = *(const float2*)(w + 2);
        float2 wc = *(const float2*)(w + 4);
        float b = b2w[i * 256 + o];
#pragma unroll
        for (int te = 0; te < TE; te += 2) {
            float dx = b, dy = b;
            dx = fmaf(eareg[te][0], wa.x, dx); dy = fmaf(eareg[te + 1][0], wa.x, dy);
            dx = fmaf(eareg[te][1], wa.y, dx); dy = fmaf(eareg[te + 1][1], wa.y, dy);
            dx = fmaf(eareg[te][2], wb.x, dx); dy = fmaf(eareg[te + 1][2], wb.x, dy);
            dx = fmaf(eareg[te][3], wb.y, dx); dy = fmaf(eareg[te + 1][3], wb.y, dy);
            dx = fmaf(eareg[te][4], wc.x, dx); dy = fmaf(eareg[te + 1][4], wc.x, dy);
            dx = fmaf(eareg[te][5], wc.y, dx); dy = fmaf(eareg[te + 1][5], wc.y, dy);
            dx = fmaxf(dx, 0.f);               dy = fmaxf(dy, 0.f);
            acc[te] = fmaf(xs[te][i], dx, acc[te]);
            acc[te + 1] = fmaf(xs[te + 1][i], dy, acc[te + 1]);
        }
    }
    if (ic > 0) {
#pragma unroll
        for (int te = 0; te < TE; te++) part[ic - 1][te][ol] = acc[te];
    }
    __syncthreads();
    if (ic == 0) {
#pragma unroll
        for (int te = 0; te < TE; te++) {
            float s = acc[te];
#pragma unroll
            for (int p = 0; p < 7; p++) s += part[p][te][ol];
            atomicAdd(agg2 + dsts[te] * 256 + o, s);
        }
    }
}

// Layer 3 (+x2 slice via lin2T): blocks 0..475 msg units; 476..510 x2m writers.
__global__ __launch_bounds__(512, 4) void msg3x2_k(
    const float* __restrict__ x, const float* __restrict__ ea,
    const int* __restrict__ ei, const float* __restrict__ lin1,
    const float* __restrict__ b1, const float* __restrict__ agg1,
    const float* __restrict__ cnt, const float* __restrict__ lin2T,
    const float* __restrict__ b2, const float* __restrict__ agg2,
    const float* __restrict__ w3, const float* __restrict__ b3w,
    float* __restrict__ agg3, float* __restrict__ x2m) {
    __shared__ float x1r[TE][256];
    __shared__ float xs[TE][64];
    __shared__ float eas[TE][6];
    __shared__ int srcs[TE], dsts[TE];
    __shared__ float part[7][TE][64];
    int tid = threadIdx.x;

    if (blockIdx.x >= NU2) {
        int n = blockIdx.x - NU2;
        float c = fmaxf(cnt[n], 1.f);
        if (tid < 256) {
            float v = agg1[n * 256 + tid] / c + x[n] * lin1[tid] + b1[tid];
            x1r[0][tid] = fmaxf(v, 0.f);
        }
        __syncthreads();
        int o = tid & 255, ic = tid >> 8;
        float s = 0.f;
        for (int ii = 0; ii < 128; ii++) {
            int i = ic * 128 + ii;
            s = fmaf(lin2T[i * 256 + o], x1r[0][i], s);
        }
        float* p2 = &part[0][0][0];
        if (ic == 1) p2[o] = s;
        __syncthreads();
        if (ic == 0) {
            float v = agg2[n * 256 + o] / c + s + p2[o] + b2[o];
            x2m[n * 256 + o] = fmaxf(v, 0.f);
        }
        return;
    }

    int eg = blockIdx.x >> 2, ig = blockIdx.x & 3;
    int e0 = eg * TE;
    if (tid < TE) { srcs[tid] = ei[e0 + tid]; dsts[tid] = ei[NE + e0 + tid]; }
    if (tid >= 64 && tid < 64 + TE * 6) {
        int t = tid - 64;
        eas[t / 6][t % 6] = ea[e0 * 6 + t];
    }
    __syncthreads();
    for (int idx = tid; idx < TE * 256; idx += 512) {
        int te = idx >> 8, i = idx & 255;
        int s = srcs[te];
        float c = fmaxf(cnt[s], 1.f);
        float v = agg1[s * 256 + i] / c + x[s] * lin1[i] + b1[i];
        x1r[te][i] = fmaxf(v, 0.f);
    }
    __syncthreads();
    int ol = tid & 63;
    int ic = tid >> 6;
    int o2 = ig * 64 + ol;
    {
        float acc2[TE] = {};
        for (int ii = 0; ii < 32; ii++) {
            int i = ic * 32 + ii;
            float w = lin2T[i * 256 + o2];
#pragma unroll
            for (int te = 0; te < TE; te++)
                acc2[te] = fmaf(w, x1r[te][i], acc2[te]);
        }
        if (ic > 0) {
#pragma unroll
            for (int te = 0; te < TE; te++) part[ic - 1][te][ol] = acc2[te];
        }
        __syncthreads();
        if (ic == 0) {
#pragma unroll
            for (int te = 0; te < TE; te++) {
                float ssum = acc2[te];
#pragma unroll
                for (int p = 0; p < 7; p++) ssum += part[p][te][ol];
                int s = srcs[te];
                float c = fmaxf(cnt[s], 1.f);
                float v = agg2[s * 256 + o2] / c + ssum + b2[o2];
                xs[te][ol] = fmaxf(v, 0.f);
            }
        }
        __syncthreads();
    }
    float eareg[TE][6];
#pragma unroll
    for (int te = 0; te < TE; te++)
#pragma unroll
        for (int v = 0; v < 6; v++) eareg[te][v] = eas[te][v];
    float acc[TE] = {};
    for (int jj = 0; jj < 8; jj++) {
        int ii = ic * 8 + jj;
        int i = ig * 64 + ii;
        const float* w = w3 + (size_t)(i * 64 + ol) * 6;
        float2 wa = *(const float2*)w;
        float2 wb = *(const float2*)(w + 2);
        float2 wc = *(const float2*)(w + 4);
        float b = b3w[i * 64 + ol];
#pragma unroll
        for (int te = 0; te < TE; te += 2) {
            float dx = b, dy = b;
            dx = fmaf(eareg[te][0], wa.x, dx); dy = fmaf(eareg[te + 1][0], wa.x, dy);
            dx = fmaf(eareg[te][1], wa.y, dx); dy = fmaf(eareg[te + 1][1], wa.y, dy);
            dx = fmaf(eareg[te][2], wb.x, dx); dy = fmaf(eareg[te + 1][2], wb.x, dy);
            dx = fmaf(eareg[te][3], wb.y, dx); dy = fmaf(eareg[te + 1][3], wb.y, dy);
            dx = fmaf(eareg[te][4], wc.x, dx); dy = fmaf(eareg[te + 1][4], wc.x, dy);
            dx = fmaf(eareg[te][5], wc.y, dx); dy = fmaf(eareg[te + 1][5], wc.y, dy);
            dx = fmaxf(dx, 0.f);               dy = fmaxf(dy, 0.f);
            acc[te] = fmaf(xs[te][ii], dx, acc[te]);
            acc[te + 1] = fmaf(xs[te + 1][ii], dy, acc[te + 1]);
        }
    }
    if (ic > 0) {
#pragma unroll
        for (int te = 0; te < TE; te++) part[ic - 1][te][ol] = acc[te];
    }
    __syncthreads();
    if (ic == 0) {
#pragma unroll
        for (int te = 0; te < TE; te++) {
            float s = acc[te];
#pragma unroll
            for (int p = 0; p < 7; p++) s += part[p][te][ol];
            atomicAdd(agg3 + dsts[te] * 64 + ol, s);
        }
    }
}

// Fused x3+cbt: 35 blocks x 512. Each block recomputes the full x3 tile
// (35x64, via lane-coalesced lin3T — NOT the round-4 per-lane row gather)
// into padded LDS, then writes its own CBT row.
__global__ __launch_bounds__(512) void x3cbt_k(
    const float* __restrict__ x2m, const float* __restrict__ lin3T,
    const float* __restrict__ b3, const float* __restrict__ agg3,
    const float* __restrict__ cnt, float* __restrict__ out) {
    __shared__ float x2s[NN * 256];   // 35840 B
    __shared__ float x3s[NN * 65];    // padded pitch 65 -> conflict-free
    int tid = threadIdx.x;
    for (int idx = tid; idx < NN * 256; idx += 512) x2s[idx] = x2m[idx];
    __syncthreads();
    for (int idx = tid; idx < NN * 64; idx += 512) {
        int n = idx >> 6, o = idx & 63;    // lanes span o -> coalesced lin3T
        const float* xr = x2s + n * 256;
        float s0 = 0.f, s1 = 0.f;
        for (int i = 0; i < 256; i += 2) {
            s0 = fmaf(lin3T[i * 64 + o], xr[i], s0);
            s1 = fmaf(lin3T[(i + 1) * 64 + o], xr[i + 1], s1);
        }
        float c = fmaxf(cnt[n], 1.f);
        x3s[n * 65 + o] = fmaxf(agg3[idx] / c + s0 + s1 + b3[o], 0.f);
    }
    __syncthreads();
    int i = blockIdx.x;
    for (int j = tid; j < NN; j += 512) {
        const float* a = x3s + i * 65;
        const float* b = x3s + j * 65;
        float s = 0.f;
#pragma unroll
        for (int f = 0; f < 64; f++) s += fabsf(a[f] - b[f]);
        out[i * NN + j] = s;
    }
}

extern "C" void kernel_launch(void* const* d_in, const int* in_sizes, int n_in,
                              void* d_out, int out_size, void* d_ws, size_t ws_size,
                              hipStream_t stream) {
    const float* x    = (const float*)d_in[0];
    const float* ea   = (const float*)d_in[1];
    const int*   ei   = (const int*)d_in[2];
    const float* nn1w = (const float*)d_in[3];
    const float* nn1b = (const float*)d_in[4];
    const float* lin1 = (const float*)d_in[5];
    const float* b1   = (const float*)d_in[6];
    const float* nn2w = (const float*)d_in[7];
    const float* nn2b = (const float*)d_in[8];
    const float* lin2 = (const float*)d_in[9];
    const float* b2   = (const float*)d_in[10];
    const float* nn3w = (const float*)d_in[11];
    const float* nn3b = (const float*)d_in[12];
    const float* lin3 = (const float*)d_in[13];
    const float* b3   = (const float*)d_in[14];

    float* ws    = (float*)d_ws;
    float* agg1  = ws + OFF_AGG1;
    float* agg2  = ws + OFF_AGG2;
    float* agg3  = ws + OFF_AGG3;
    float* cnt   = ws + OFF_CNT;
    float* lin2T = ws + OFF_L2T;
    float* x2m   = ws + OFF_X2M;
    float* lin3T = ws + OFF_L3T;
    float* out   = (float*)d_out;

    prep_k<<<80, 256, 0, stream>>>(ws);
    msg1t_k<<<755, 512, 0, stream>>>(x, ea, ei, nn1w, nn1b, lin2, lin3, ws);
    msg2x1_k<<<NG * 4, 512, 0, stream>>>(x, ea, ei, lin1, b1, agg1, cnt,
                                         nn2w, nn2b, agg2);
    msg3x2_k<<<NG * 4 + NN, 512, 0, stream>>>(x, ea, ei, lin1, b1, agg1, cnt,
                                              lin2T, b2, agg2, nn3w, nn3b,
                                              agg3, x2m);
    x3cbt_k<<<NN, 512, 0, stream>>>(x2m, lin3T, b3, agg3, cnt, out);
}

// Round 9
// 143.675 us; speedup vs baseline: 2.1732x; 1.0887x over previous
//
#include <hip/hip_runtime.h>

// MGN_NET: 3x NNConv(mean) + ReLU, then pairwise-L1 CBT [35x35]. All fp32.
// 6 dispatches: prep(zero) -> msg1(+lin2 transpose blocks) -> msg2(+x1) ->
//               msg3(+x2 slice, +x2m writers) -> x3 -> cbt
// Lessons baked in: R7 grid.sync ~35us each on gfx950 (never cooperative for
// ~30us of work); R4/R8 single-CU or 35x-redundant latency-bound recompute
// fusions lose 5-20us to save a ~3.5us dispatch. Round-6 structure = best.
// ws layout (floats): agg1@0[8960], agg2@8960[8960], agg3@17920[2240],
//   cnt@20160[35] (zero span 20195), lin2T@20224[65536], x2m@85760[8960],
//   x3@94720[2240]

#define NN 35
#define NE 1190
#define TE 10   // edges per edge-group; 1190 = 119*10
#define NG 119
#define NU2 476 // msg2/msg3 msg units: 119 eg x 4 og/ig

#define OFF_AGG1 0
#define OFF_AGG2 8960
#define OFF_AGG3 17920
#define OFF_CNT  20160
#define ZERO_N   20195
#define OFF_L2T  20224
#define OFF_X2M  85760
#define OFF_X3   94720

// prep: zero accumulators (80 blocks x 256)
__global__ __launch_bounds__(256) void prep_k(float* __restrict__ ws) {
    int idx = blockIdx.x * 256 + threadIdx.x;
    if (idx < ZERO_N) ws[idx] = 0.f;
}

// msg1 (blocks 0..594: 2 edges x 256 o) + lin2 transpose (blocks 595..722):
// lin2T[i][o] = lin2[o][i]; writes coalesced, reads gathered (as R6 prep).
__global__ __launch_bounds__(512) void msg1t_k(
    const float* __restrict__ x, const float* __restrict__ ea,
    const int* __restrict__ ei, const float* __restrict__ w1,
    const float* __restrict__ b1w, const float* __restrict__ lin2,
    float* __restrict__ ws) {
    int tid = threadIdx.x;
    if (blockIdx.x >= 595) {
        int bb = blockIdx.x - 595;             // [0,128)
        int i = bb * 2 + (tid >> 8);           // row of lin2T
        int o = tid & 255;
        ws[OFF_L2T + i * 256 + o] = lin2[o * 256 + i];
        return;
    }
    float* agg1 = ws + OFF_AGG1;
    float* cnt  = ws + OFF_CNT;
    int e = blockIdx.x * 2 + (tid >> 8);
    int o = tid & 255;
    int src = ei[e];
    int dst = ei[NE + e];
    float xs = x[src];
    const float* eap = ea + e * 6;
    const float* w = w1 + o * 6;
    float d = b1w[o];
#pragma unroll
    for (int v = 0; v < 6; v++) d = fmaf(eap[v], w[v], d);
    atomicAdd(agg1 + dst * 256 + o, xs * fmaxf(d, 0.f));
    if (o == 0) atomicAdd(cnt + dst, 1.0f);
}

// Layer 2 (+x1 recompute): grid 119 eg x 4 og; block 512 = 64 ol x 8 ic.
__global__ __launch_bounds__(512, 4) void msg2x1_k(
    const float* __restrict__ x, const float* __restrict__ ea,
    const int* __restrict__ ei, const float* __restrict__ lin1,
    const float* __restrict__ b1, const float* __restrict__ agg1,
    const float* __restrict__ cnt, const float* __restrict__ w2,
    const float* __restrict__ b2w, float* __restrict__ agg2) {
    __shared__ float xs[TE][256];
    __shared__ float eas[TE][6];
    __shared__ int srcs[TE], dsts[TE];
    __shared__ float part[7][TE][64];
    int tid = threadIdx.x;
    int eg = blockIdx.x >> 2, og = blockIdx.x & 3;
    int e0 = eg * TE;
    if (tid < TE) { srcs[tid] = ei[e0 + tid]; dsts[tid] = ei[NE + e0 + tid]; }
    if (tid >= 64 && tid < 64 + TE * 6) {
        int t = tid - 64;
        eas[t / 6][t % 6] = ea[e0 * 6 + t];
    }
    __syncthreads();
    for (int idx = tid; idx < TE * 256; idx += 512) {
        int te = idx >> 8, i = idx & 255;
        int s = srcs[te];
        float c = fmaxf(cnt[s], 1.f);
        float v = agg1[s * 256 + i] / c + x[s] * lin1[i] + b1[i];
        xs[te][i] = fmaxf(v, 0.f);
    }
    __syncthreads();
    int ol = tid & 63;
    int o = og * 64 + ol;
    int ic = tid >> 6;
    float eareg[TE][6];
#pragma unroll
    for (int te = 0; te < TE; te++)
#pragma unroll
        for (int v = 0; v < 6; v++) eareg[te][v] = eas[te][v];
    float acc[TE] = {};
    for (int ii = 0; ii < 32; ii++) {
        int i = ic * 32 + ii;
        const float* w = w2 + (size_t)(i * 256 + o) * 6;
        float2 wa = *(const float2*)w;
        float2 wb = *(const float2*)(w + 2);
        float2 wc = *(const float2*)(w + 4);
        float b = b2w[i * 256 + o];
#pragma unroll
        for (int te = 0; te < TE; te += 2) {
            float dx = b, dy = b;
            dx = fmaf(eareg[te][0], wa.x, dx); dy = fmaf(eareg[te + 1][0], wa.x, dy);
            dx = fmaf(eareg[te][1], wa.y, dx); dy = fmaf(eareg[te + 1][1], wa.y, dy);
            dx = fmaf(eareg[te][2], wb.x, dx); dy = fmaf(eareg[te + 1][2], wb.x, dy);
            dx = fmaf(eareg[te][3], wb.y, dx); dy = fmaf(eareg[te + 1][3], wb.y, dy);
            dx = fmaf(eareg[te][4], wc.x, dx); dy = fmaf(eareg[te + 1][4], wc.x, dy);
            dx = fmaf(eareg[te][5], wc.y, dx); dy = fmaf(eareg[te + 1][5], wc.y, dy);
            dx = fmaxf(dx, 0.f);               dy = fmaxf(dy, 0.f);
            acc[te] = fmaf(xs[te][i], dx, acc[te]);
            acc[te + 1] = fmaf(xs[te + 1][i], dy, acc[te + 1]);
        }
    }
    if (ic > 0) {
#pragma unroll
        for (int te = 0; te < TE; te++) part[ic - 1][te][ol] = acc[te];
    }
    __syncthreads();
    if (ic == 0) {
#pragma unroll
        for (int te = 0; te < TE; te++) {
            float s = acc[te];
#pragma unroll
            for (int p = 0; p < 7; p++) s += part[p][te][ol];
            atomicAdd(agg2 + dsts[te] * 256 + o, s);
        }
    }
}

// Layer 3 (+x2 slice via lin2T): blocks 0..475 msg units; 476..510 x2m writers.
__global__ __launch_bounds__(512, 4) void msg3x2_k(
    const float* __restrict__ x, const float* __restrict__ ea,
    const int* __restrict__ ei, const float* __restrict__ lin1,
    const float* __restrict__ b1, const float* __restrict__ agg1,
    const float* __restrict__ cnt, const float* __restrict__ lin2T,
    const float* __restrict__ b2, const float* __restrict__ agg2,
    const float* __restrict__ w3, const float* __restrict__ b3w,
    float* __restrict__ agg3, float* __restrict__ x2m) {
    __shared__ float x1r[TE][256];
    __shared__ float xs[TE][64];
    __shared__ float eas[TE][6];
    __shared__ int srcs[TE], dsts[TE];
    __shared__ float part[7][TE][64];
    int tid = threadIdx.x;

    if (blockIdx.x >= NU2) {
        int n = blockIdx.x - NU2;
        float c = fmaxf(cnt[n], 1.f);
        if (tid < 256) {
            float v = agg1[n * 256 + tid] / c + x[n] * lin1[tid] + b1[tid];
            x1r[0][tid] = fmaxf(v, 0.f);
        }
        __syncthreads();
        int o = tid & 255, ic = tid >> 8;
        float s = 0.f;
        for (int ii = 0; ii < 128; ii++) {
            int i = ic * 128 + ii;
            s = fmaf(lin2T[i * 256 + o], x1r[0][i], s);
        }
        float* p2 = &part[0][0][0];
        if (ic == 1) p2[o] = s;
        __syncthreads();
        if (ic == 0) {
            float v = agg2[n * 256 + o] / c + s + p2[o] + b2[o];
            x2m[n * 256 + o] = fmaxf(v, 0.f);
        }
        return;
    }

    int eg = blockIdx.x >> 2, ig = blockIdx.x & 3;
    int e0 = eg * TE;
    if (tid < TE) { srcs[tid] = ei[e0 + tid]; dsts[tid] = ei[NE + e0 + tid]; }
    if (tid >= 64 && tid < 64 + TE * 6) {
        int t = tid - 64;
        eas[t / 6][t % 6] = ea[e0 * 6 + t];
    }
    __syncthreads();
    for (int idx = tid; idx < TE * 256; idx += 512) {
        int te = idx >> 8, i = idx & 255;
        int s = srcs[te];
        float c = fmaxf(cnt[s], 1.f);
        float v = agg1[s * 256 + i] / c + x[s] * lin1[i] + b1[i];
        x1r[te][i] = fmaxf(v, 0.f);
    }
    __syncthreads();
    int ol = tid & 63;
    int ic = tid >> 6;
    int o2 = ig * 64 + ol;
    {
        float acc2[TE] = {};
        for (int ii = 0; ii < 32; ii++) {
            int i = ic * 32 + ii;
            float w = lin2T[i * 256 + o2];
#pragma unroll
            for (int te = 0; te < TE; te++)
                acc2[te] = fmaf(w, x1r[te][i], acc2[te]);
        }
        if (ic > 0) {
#pragma unroll
            for (int te = 0; te < TE; te++) part[ic - 1][te][ol] = acc2[te];
        }
        __syncthreads();
        if (ic == 0) {
#pragma unroll
            for (int te = 0; te < TE; te++) {
                float ssum = acc2[te];
#pragma unroll
                for (int p = 0; p < 7; p++) ssum += part[p][te][ol];
                int s = srcs[te];
                float c = fmaxf(cnt[s], 1.f);
                float v = agg2[s * 256 + o2] / c + ssum + b2[o2];
                xs[te][ol] = fmaxf(v, 0.f);
            }
        }
        __syncthreads();
    }
    float eareg[TE][6];
#pragma unroll
    for (int te = 0; te < TE; te++)
#pragma unroll
        for (int v = 0; v < 6; v++) eareg[te][v] = eas[te][v];
    float acc[TE] = {};
    for (int jj = 0; jj < 8; jj++) {
        int ii = ic * 8 + jj;
        int i = ig * 64 + ii;
        const float* w = w3 + (size_t)(i * 64 + ol) * 6;
        float2 wa = *(const float2*)w;
        float2 wb = *(const float2*)(w + 2);
        float2 wc = *(const float2*)(w + 4);
        float b = b3w[i * 64 + ol];
#pragma unroll
        for (int te = 0; te < TE; te += 2) {
            float dx = b, dy = b;
            dx = fmaf(eareg[te][0], wa.x, dx); dy = fmaf(eareg[te + 1][0], wa.x, dy);
            dx = fmaf(eareg[te][1], wa.y, dx); dy = fmaf(eareg[te + 1][1], wa.y, dy);
            dx = fmaf(eareg[te][2], wb.x, dx); dy = fmaf(eareg[te + 1][2], wb.x, dy);
            dx = fmaf(eareg[te][3], wb.y, dx); dy = fmaf(eareg[te + 1][3], wb.y, dy);
            dx = fmaf(eareg[te][4], wc.x, dx); dy = fmaf(eareg[te + 1][4], wc.x, dy);
            dx = fmaf(eareg[te][5], wc.y, dx); dy = fmaf(eareg[te + 1][5], wc.y, dy);
            dx = fmaxf(dx, 0.f);               dy = fmaxf(dy, 0.f);
            acc[te] = fmaf(xs[te][ii], dx, acc[te]);
            acc[te + 1] = fmaf(xs[te + 1][ii], dy, acc[te + 1]);
        }
    }
    if (ic > 0) {
#pragma unroll
        for (int te = 0; te < TE; te++) part[ic - 1][te][ol] = acc[te];
    }
    __syncthreads();
    if (ic == 0) {
#pragma unroll
        for (int te = 0; te < TE; te++) {
            float s = acc[te];
#pragma unroll
            for (int p = 0; p < 7; p++) s += part[p][te][ol];
            atomicAdd(agg3 + dsts[te] * 64 + ol, s);
        }
    }
}

// x3: 35 blocks x 256 thr (64 o x 4 i-chunks); per-lane lin3 row gather is
// fine at this block count (35 CUs' L1s in parallel).
__global__ __launch_bounds__(256) void x3_k(
    const float* __restrict__ x2m, const float* __restrict__ lin3,
    const float* __restrict__ b3, const float* __restrict__ agg3,
    const float* __restrict__ cnt, float* __restrict__ x3) {
    __shared__ float xr[256];
    __shared__ float part[3][64];
    int n = blockIdx.x, tid = threadIdx.x;
    int o = tid & 63, ic = tid >> 6;
    xr[tid] = x2m[n * 256 + tid];
    __syncthreads();
    const float4* w = (const float4*)(lin3 + (size_t)o * 256 + ic * 64);
    float s = 0.f;
#pragma unroll
    for (int k = 0; k < 16; k++) {
        float4 wv = w[k];
        int i = ic * 64 + k * 4;
        s = fmaf(wv.x, xr[i], s);
        s = fmaf(wv.y, xr[i + 1], s);
        s = fmaf(wv.z, xr[i + 2], s);
        s = fmaf(wv.w, xr[i + 3], s);
    }
    if (ic > 0) part[ic - 1][o] = s;
    __syncthreads();
    if (ic == 0) {
        float tot = s + part[0][o] + part[1][o] + part[2][o];
        float c = fmaxf(cnt[n], 1.f);
        x3[n * 64 + o] = fmaxf(agg3[n * 64 + o] / c + tot + b3[o], 0.f);
    }
}

__global__ __launch_bounds__(256) void cbt_k(const float* __restrict__ x3,
                                             float* __restrict__ out) {
    int t = blockIdx.x * 256 + threadIdx.x;
    if (t >= NN * NN) return;
    int i = t / NN, j = t % NN;
    const float* a = x3 + i * 64;
    const float* b = x3 + j * 64;
    float s = 0.f;
#pragma unroll
    for (int f = 0; f < 64; f++) s += fabsf(a[f] - b[f]);
    out[t] = s;
}

extern "C" void kernel_launch(void* const* d_in, const int* in_sizes, int n_in,
                              void* d_out, int out_size, void* d_ws, size_t ws_size,
                              hipStream_t stream) {
    const float* x    = (const float*)d_in[0];
    const float* ea   = (const float*)d_in[1];
    const int*   ei   = (const int*)d_in[2];
    const float* nn1w = (const float*)d_in[3];
    const float* nn1b = (const float*)d_in[4];
    const float* lin1 = (const float*)d_in[5];
    const float* b1   = (const float*)d_in[6];
    const float* nn2w = (const float*)d_in[7];
    const float* nn2b = (const float*)d_in[8];
    const float* lin2 = (const float*)d_in[9];
    const float* b2   = (const float*)d_in[10];
    const float* nn3w = (const float*)d_in[11];
    const float* nn3b = (const float*)d_in[12];
    const float* lin3 = (const float*)d_in[13];
    const float* b3   = (const float*)d_in[14];

    float* ws    = (float*)d_ws;
    float* agg1  = ws + OFF_AGG1;
    float* agg2  = ws + OFF_AGG2;
    float* agg3  = ws + OFF_AGG3;
    float* cnt   = ws + OFF_CNT;
    float* lin2T = ws + OFF_L2T;
    float* x2m   = ws + OFF_X2M;
    float* x3v   = ws + OFF_X3;
    float* out   = (float*)d_out;

    prep_k<<<80, 256, 0, stream>>>(ws);
    msg1t_k<<<723, 512, 0, stream>>>(x, ea, ei, nn1w, nn1b, lin2, ws);
    msg2x1_k<<<NG * 4, 512, 0, stream>>>(x, ea, ei, lin1, b1, agg1, cnt,
                                         nn2w, nn2b, agg2);
    msg3x2_k<<<NG * 4 + NN, 512, 0, stream>>>(x, ea, ei, lin1, b1, agg1, cnt,
                                              lin2T, b2, agg2, nn3w, nn3b,
                                              agg3, x2m);
    x3_k<<<NN, 256, 0, stream>>>(x2m, lin3, b3, agg3, cnt, x3v);
    cbt_k<<<(NN * NN + 255) / 256, 256, 0, stream>>>(x3v, out);
}